// Round 5
// baseline (174.690 us; speedup 1.0000x reference)
//
#include <hip/hip_runtime.h>
#include <math.h>

#define HIDDEN 64
#define RANGE 16384       // nodes per LDS bin range (64 KB f32 bins), 2^14
#define RSHIFT 14
#define G 32              // chunks per range in the binning passes
#define NSEG 256          // segments (blocks) for the counting sort
#define MAXR 8            // max ranges supported (N <= 131072: src fits 17 bits)

// ---------------------------------------------------------------------------
// Counting sort of edges by dst-range (7 buckets for N=100000).
// Packing: sorted edge = (dst_local << 17) | src  (14 + 17 = 31 bits), + ew.
// ---------------------------------------------------------------------------

// Per-segment histogram of dst ranges.
__global__ void k_hist(const int* __restrict__ dst, int* __restrict__ counts,
                       int E, int nranges) {
    __shared__ int h[MAXR];
    if (threadIdx.x < MAXR) h[threadIdx.x] = 0;
    __syncthreads();
    int e0 = (int)((long long)E * blockIdx.x / NSEG);
    int e1 = (int)((long long)E * (blockIdx.x + 1) / NSEG);
    for (int e = e0 + threadIdx.x; e < e1; e += blockDim.x)
        atomicAdd(&h[dst[e] >> RSHIFT], 1);
    __syncthreads();
    if (threadIdx.x < MAXR) counts[blockIdx.x * MAXR + threadIdx.x] = h[threadIdx.x];
}

// Exclusive scan: offs[seg][b] = bucket_base[b] + sum_{seg'<seg} counts[seg'][b].
// Also emits bucket bases (bbase[0..nranges], bbase[nranges]=E).
__global__ __launch_bounds__(NSEG) void k_scan(const int* __restrict__ counts,
                                               int* __restrict__ offs,
                                               int* __restrict__ bbase) {
    __shared__ int sh[NSEG][MAXR];
    __shared__ int base[MAXR + 1];
    int t = threadIdx.x;
    int own[MAXR];
    #pragma unroll
    for (int b = 0; b < MAXR; ++b) { own[b] = counts[t * MAXR + b]; sh[t][b] = own[b]; }
    __syncthreads();
    for (int step = 1; step < NSEG; step <<= 1) {
        int v[MAXR];
        if (t >= step) {
            #pragma unroll
            for (int b = 0; b < MAXR; ++b) v[b] = sh[t - step][b];
        }
        __syncthreads();
        if (t >= step) {
            #pragma unroll
            for (int b = 0; b < MAXR; ++b) sh[t][b] += v[b];
        }
        __syncthreads();
    }
    if (t == 0) {
        int a = 0;
        #pragma unroll
        for (int b = 0; b < MAXR; ++b) { base[b] = a; a += sh[NSEG - 1][b]; }
        base[MAXR] = a;
    }
    __syncthreads();
    #pragma unroll
    for (int b = 0; b < MAXR; ++b) offs[t * MAXR + b] = base[b] + sh[t][b] - own[b];
    if (t < MAXR + 1) bbase[t] = base[t];
}

// Scatter edges into bucket-sorted (pack, ew) arrays.
__global__ void k_scatter(const int* __restrict__ dst, const int* __restrict__ src,
                          const float* __restrict__ ew, const int* __restrict__ offs,
                          unsigned* __restrict__ spack, float* __restrict__ sew, int E) {
    __shared__ int cur[MAXR];
    if (threadIdx.x < MAXR) cur[threadIdx.x] = offs[blockIdx.x * MAXR + threadIdx.x];
    __syncthreads();
    int e0 = (int)((long long)E * blockIdx.x / NSEG);
    int e1 = (int)((long long)E * (blockIdx.x + 1) / NSEG);
    for (int e = e0 + threadIdx.x; e < e1; e += blockDim.x) {
        int d = dst[e];
        int pos = atomicAdd(&cur[d >> RSHIFT], 1);
        spack[pos] = ((unsigned)(d & (RANGE - 1)) << 17) | (unsigned)src[e];
        sew[pos] = ew[e];
    }
}

// ---------------------------------------------------------------------------
// Binning scatter-add over sorted buckets: zero read waste, no filtering.
// Grid = nranges*G, blockIdx = r*G + c. Flush to private partials slice.
// ---------------------------------------------------------------------------
template <bool WEIGHTED>
__global__ __launch_bounds__(1024)
void k_bin(const unsigned* __restrict__ spack, const float* __restrict__ sew,
           const float* __restrict__ w, const int* __restrict__ bbase,
           float* __restrict__ partials, int nranges) {
    __shared__ float bins[RANGE];
    float4* b4 = (float4*)bins;
    for (int i = threadIdx.x; i < RANGE / 4; i += blockDim.x)
        b4[i] = make_float4(0.f, 0.f, 0.f, 0.f);
    __syncthreads();

    const int r = blockIdx.x / G, c = blockIdx.x % G;
    const int s = bbase[r];
    const int len = bbase[r + 1] - s;
    const int a0 = s + (int)((long long)len * c / G);
    const int a1 = s + (int)((long long)len * (c + 1) / G);

    for (int e = a0 + threadIdx.x; e < a1; e += blockDim.x) {
        unsigned p = spack[e];
        float v = sew[e];
        if (WEIGHTED) v *= w[p & 0x1FFFFu];
        atomicAdd(&bins[p >> 17], v);   // ds_add_f32
    }
    __syncthreads();

    float4* outp = (float4*)(partials + ((size_t)c * nranges + r) * RANGE);
    for (int i = threadIdx.x; i < RANGE / 4; i += blockDim.x) outp[i] = b4[i];
}

// ---------------------------------------------------------------------------
// Reduce deg partials -> dinv = rsqrt(deg+1), w = dinv*x.
// Block 0 also computes fused GRU coefficients (H0=0 => only top 64 rows of
// Lz/Lh matter; the R gate is dead code).
// ---------------------------------------------------------------------------
__global__ void k_node(const float* __restrict__ x, const float* __restrict__ partials,
                       float* __restrict__ dinv, float* __restrict__ w,
                       int N, int nranges,
                       const float* __restrict__ Wz, const float* __restrict__ bz,
                       const float* __restrict__ Lz, const float* __restrict__ lbz,
                       const float* __restrict__ Wh, const float* __restrict__ bh,
                       const float* __restrict__ Lh, const float* __restrict__ lbh,
                       float* __restrict__ coeff) {
    int i = blockIdx.x * blockDim.x + threadIdx.x;
    if (i < N) {
        int r = i >> RSHIFT, local = i & (RANGE - 1);
        const float* p = partials + (size_t)r * RANGE + local;
        float d = 1.0f;   // self-loop
        #pragma unroll
        for (int c = 0; c < G; ++c) d += p[(size_t)c * nranges * RANGE];
        float di = rsqrtf(d);
        dinv[i] = di;
        w[i] = di * x[i];
    }
    if (blockIdx.x == 0 && threadIdx.x < HIDDEN) {
        int j = threadIdx.x;
        float vz = 0.f, cz = 0.f, vh = 0.f, ch = 0.f;
        for (int k = 0; k < HIDDEN; ++k) {
            float lz = Lz[k * HIDDEN + j];
            float lh = Lh[k * HIDDEN + j];
            vz += Wz[k] * lz;
            cz += bz[k] * lz;
            vh += Wh[k] * lh;
            ch += bh[k] * lh;
        }
        coeff[j]       = vz;
        coeff[64 + j]  = cz + lbz[j];
        coeff[128 + j] = vh;
        coeff[192 + j] = ch + lbh[j];
    }
}

// ---------------------------------------------------------------------------
// Reduce agg partials, add self-loop, fused GRU + output head:
//   s = dinv*(sum_c P[c][i] + w[i]),
//   out[i] = sum_j relu(sigmoid(-zp)*tanh(hp)) * Wout_j + bout.
// ---------------------------------------------------------------------------
__global__ void k_out(const float* __restrict__ partials, const float* __restrict__ dinv,
                      const float* __restrict__ w, const float* __restrict__ coeff,
                      const float* __restrict__ Wout, const float* __restrict__ bout,
                      float* __restrict__ out, int N, int nranges) {
    __shared__ float c[5 * HIDDEN];
    __shared__ float b0;
    if (threadIdx.x < 4 * HIDDEN) c[threadIdx.x] = coeff[threadIdx.x];
    if (threadIdx.x < HIDDEN) c[4 * HIDDEN + threadIdx.x] = Wout[threadIdx.x];
    if (threadIdx.x == 0) b0 = bout[0];
    __syncthreads();
    int i = blockIdx.x * blockDim.x + threadIdx.x;
    if (i < N) {
        int r = i >> RSHIFT, local = i & (RANGE - 1);
        const float* p = partials + (size_t)r * RANGE + local;
        float g = w[i];
        #pragma unroll
        for (int k = 0; k < G; ++k) g += p[(size_t)k * nranges * RANGE];
        float si = dinv[i] * g;
        float acc = b0;
        #pragma unroll
        for (int j = 0; j < HIDDEN; ++j) {
            float zp = fminf(fmaxf(si * c[j] + c[64 + j], -30.f), 30.f);
            float hp = fminf(fmaxf(si * c[128 + j] + c[192 + j], -15.f), 15.f);
            float a  = __expf(2.0f * hp);               // tanh(hp)=(a-1)/(a+1)
            float t  = (a - 1.0f) / (a + 1.0f);
            float zn = 1.0f / (1.0f + __expf(zp));      // 1 - sigmoid(zp)
            float hn = zn * t;
            hn = hn > 0.0f ? hn : 0.0f;
            acc = fmaf(hn, c[256 + j], acc);
        }
        out[i] = acc;
    }
}

extern "C" void kernel_launch(void* const* d_in, const int* in_sizes, int n_in,
                              void* d_out, int out_size, void* d_ws, size_t ws_size,
                              hipStream_t stream) {
    const float* x    = (const float*)d_in[0];
    const float* ew   = (const float*)d_in[1];
    const float* Wz   = (const float*)d_in[2];
    const float* bz   = (const float*)d_in[3];
    const float* Lz   = (const float*)d_in[4];
    const float* lbz  = (const float*)d_in[5];
    // d_in[6..9] = Wr, br, Lr, lbr — dead (H0 = 0 makes the R gate unused)
    const float* Wh   = (const float*)d_in[10];
    const float* bh   = (const float*)d_in[11];
    const float* Lh   = (const float*)d_in[12];
    const float* lbh  = (const float*)d_in[13];
    const float* Wout = (const float*)d_in[14];
    const float* bout = (const float*)d_in[15];
    const int*   eidx = (const int*)d_in[16];

    const int N = in_sizes[0];          // x is [N,1]   (100000: src fits 17 bits)
    const int E = in_sizes[1];          // edge_weight is [E]
    const int* src = eidx;              // edge_index[0]
    const int* dst = eidx + E;          // edge_index[1]

    const int nranges = (N + RANGE - 1) / RANGE;   // 7

    // Workspace layout (d_ws is >= 256 MB; we use ~30 MB)
    float*    partials = (float*)d_ws;                                  // G*nranges*RANGE
    unsigned* spack    = (unsigned*)(partials + (size_t)G * nranges * RANGE);  // E
    float*    sew      = (float*)(spack + E);                           // E
    float*    dinv     = sew + E;                                       // N
    float*    w        = dinv + N;                                      // N
    float*    coeff    = w + N;                                         // 4*HIDDEN
    int*      counts   = (int*)(coeff + 4 * HIDDEN);                    // NSEG*MAXR
    int*      offs     = counts + NSEG * MAXR;                          // NSEG*MAXR
    int*      bbase    = offs + NSEG * MAXR;                            // MAXR+1

    const int TB = 256;
    const int grid_bin = nranges * G;      // 224 blocks, 64 KB LDS each

    // Counting sort by dst-range
    k_hist<<<NSEG, TB, 0, stream>>>(dst, counts, E, nranges);
    k_scan<<<1, NSEG, 0, stream>>>(counts, offs, bbase);
    k_scatter<<<NSEG, TB, 0, stream>>>(dst, src, ew, offs, spack, sew, E);

    // Pass A: deg partials from sorted buckets (no wasted reads)
    k_bin<false><<<grid_bin, 1024, 0, stream>>>(spack, sew, (const float*)nullptr,
                                                bbase, partials, nranges);
    k_node<<<(N + TB - 1) / TB, TB, 0, stream>>>(x, partials, dinv, w, N, nranges,
                                                 Wz, bz, Lz, lbz, Wh, bh, Lh, lbh, coeff);
    // Pass B: agg partials (val = w[src]*ew)
    k_bin<true><<<grid_bin, 1024, 0, stream>>>(spack, sew, w, bbase, partials, nranges);
    k_out<<<(N + TB - 1) / TB, TB, 0, stream>>>(partials, dinv, w, coeff, Wout, bout,
                                                (float*)d_out, N, nranges);
}

// Round 6
// 154.789 us; speedup vs baseline: 1.1286x; 1.1286x over previous
//
#include <hip/hip_runtime.h>
#include <math.h>

#define HIDDEN 64
#define RANGE 16384       // nodes per LDS bin range (64 KB f32 bins), 2^14
#define RSHIFT 14
#define G 32              // edge chunks (multiple of 8 for the XCD swizzle)
#define PACK_SHIFT 17     // src fits 17 bits (N <= 131072)

// Block -> (range, chunk) mapping with XCD locality: blocks are dispatched
// round-robin over the 8 XCDs by blockIdx%8 (heuristic, perf-only). We put
// all nranges blocks of chunk c on XCD c%8 so the chunk's edge stream is
// fetched into that XCD's L2 once and re-read by the other ranges from L2.
__device__ __forceinline__ void map_rc(int b, int nranges, int& r, int& c) {
    int x = b & 7;
    int rest = b >> 3;
    r = rest % nranges;
    c = x + 8 * (rest / nranges);
}

// ---------------------------------------------------------------------------
// Pass A: deg binning + in-range edge compaction (fused).
// Each (r,c) block: zero 16K LDS bins; stream chunk c with int4/float4 loads;
// for in-range edges: ds_add_f32 deg bin AND append (pack, ew) to a private
// comp slice via ballot-aggregated LDS cursor (coalesced uint2 stores).
// Flush bins to partials[c][r]; write cursor to counts[r*G+c].
// ---------------------------------------------------------------------------
__global__ __launch_bounds__(1024)
void k_binA(const int* __restrict__ dst, const int* __restrict__ src,
            const float* __restrict__ ew, float* __restrict__ partials,
            uint2* __restrict__ comp, int* __restrict__ counts,
            int N, int E, int nranges, int cap) {
    __shared__ float bins[RANGE];
    __shared__ int cursor;
    float4* b4 = (float4*)bins;
    for (int i = threadIdx.x; i < RANGE / 4; i += blockDim.x)
        b4[i] = make_float4(0.f, 0.f, 0.f, 0.f);
    if (threadIdx.x == 0) cursor = 0;
    __syncthreads();

    int r, c;
    map_rc(blockIdx.x, nranges, r, c);
    const int base = r * RANGE;
    const unsigned rsize = (unsigned)min(RANGE, N - base);
    uint2* slice = comp + (size_t)(r * G + c) * cap;

    long long e0 = (((long long)E * c) / G) & ~3LL;
    long long e1 = (c == G - 1) ? (long long)E
                                : ((((long long)E * (c + 1)) / G) & ~3LL);
    const int nvec = (int)((e1 - e0) >> 2);
    const int4*   dst4 = (const int4*)(dst + e0);
    const int4*   src4 = (const int4*)(src + e0);
    const float4* ew4  = (const float4*)(ew + e0);
    const int lane = threadIdx.x & 63;

    for (int i = threadIdx.x; i < nvec; i += blockDim.x) {
        int4   d = dst4[i];
        int4   s = src4[i];
        float4 t = ew4[i];
        int   dd[4] = {d.x, d.y, d.z, d.w};
        int   ss[4] = {s.x, s.y, s.z, s.w};
        float tt[4] = {t.x, t.y, t.z, t.w};
        #pragma unroll
        for (int j = 0; j < 4; ++j) {
            unsigned l = (unsigned)(dd[j] - base);
            bool p = l < rsize;
            if (p) atomicAdd(&bins[l], tt[j]);          // ds_add_f32 (deg)
            unsigned long long m = __ballot(p);
            if (m) {
                int leader = __ffsll((unsigned long long)m) - 1;
                int pre = __popcll(m & ((1ULL << lane) - 1ULL));
                int bpos = 0;
                if (lane == leader) bpos = atomicAdd(&cursor, __popcll(m));
                bpos = __shfl(bpos, leader);
                if (p) slice[bpos + pre] =
                    make_uint2((l << PACK_SHIFT) | (unsigned)ss[j],
                               __float_as_uint(tt[j]));
            }
        }
    }
    // scalar tail (last chunk only, < 4 edges)
    for (long long e = e0 + ((long long)nvec << 2) + threadIdx.x; e < e1; e += blockDim.x) {
        unsigned l = (unsigned)(dst[e] - base);
        if (l < rsize) {
            atomicAdd(&bins[l], ew[e]);
            int bpos = atomicAdd(&cursor, 1);
            slice[bpos] = make_uint2((l << PACK_SHIFT) | (unsigned)src[e],
                                     __float_as_uint(ew[e]));
        }
    }
    __syncthreads();

    float4* outp = (float4*)(partials + ((size_t)c * nranges + r) * RANGE);
    for (int i = threadIdx.x; i < RANGE / 4; i += blockDim.x) outp[i] = b4[i];
    if (threadIdx.x == 0) counts[r * G + c] = cursor;
}

// ---------------------------------------------------------------------------
// Reduce deg partials -> dinv = rsqrt(deg+1), w = dinv*x.
// Block 0 also computes fused GRU coefficients (H0=0 => only top 64 rows of
// Lz/Lh matter; the R gate is dead code).
// ---------------------------------------------------------------------------
__global__ void k_node(const float* __restrict__ x, const float* __restrict__ partials,
                       float* __restrict__ dinv, float* __restrict__ w,
                       int N, int nranges,
                       const float* __restrict__ Wz, const float* __restrict__ bz,
                       const float* __restrict__ Lz, const float* __restrict__ lbz,
                       const float* __restrict__ Wh, const float* __restrict__ bh,
                       const float* __restrict__ Lh, const float* __restrict__ lbh,
                       float* __restrict__ coeff) {
    int i = blockIdx.x * blockDim.x + threadIdx.x;
    if (i < N) {
        int r = i >> RSHIFT, local = i & (RANGE - 1);
        const float* p = partials + (size_t)r * RANGE + local;
        float d = 1.0f;   // self-loop
        #pragma unroll
        for (int c = 0; c < G; ++c) d += p[(size_t)c * nranges * RANGE];
        float di = rsqrtf(d);
        dinv[i] = di;
        w[i] = di * x[i];
    }
    if (blockIdx.x == 0 && threadIdx.x < HIDDEN) {
        int j = threadIdx.x;
        float vz = 0.f, cz = 0.f, vh = 0.f, ch = 0.f;
        for (int k = 0; k < HIDDEN; ++k) {
            float lz = Lz[k * HIDDEN + j];
            float lh = Lh[k * HIDDEN + j];
            vz += Wz[k] * lz;
            cz += bz[k] * lz;
            vh += Wh[k] * lh;
            ch += bh[k] * lh;
        }
        coeff[j]       = vz;
        coeff[64 + j]  = cz + lbz[j];
        coeff[128 + j] = vh;
        coeff[192 + j] = ch + lbh[j];
    }
}

// ---------------------------------------------------------------------------
// Pass B: aggregate w[src]*ew over the compacted in-range edges only.
// No filtering, no wasted reads: each (r,c) block streams its own slice.
// ---------------------------------------------------------------------------
__global__ __launch_bounds__(1024)
void k_binB(const uint2* __restrict__ comp, const int* __restrict__ counts,
            const float* __restrict__ w, float* __restrict__ partials,
            int nranges, int cap) {
    __shared__ float bins[RANGE];
    float4* b4 = (float4*)bins;
    for (int i = threadIdx.x; i < RANGE / 4; i += blockDim.x)
        b4[i] = make_float4(0.f, 0.f, 0.f, 0.f);
    __syncthreads();

    int r, c;
    map_rc(blockIdx.x, nranges, r, c);
    const uint2* slice = comp + (size_t)(r * G + c) * cap;
    const int n = counts[r * G + c];

    for (int i = threadIdx.x; i < n; i += blockDim.x) {
        uint2 e = slice[i];
        float v = w[e.x & ((1u << PACK_SHIFT) - 1u)] * __uint_as_float(e.y);
        atomicAdd(&bins[e.x >> PACK_SHIFT], v);   // ds_add_f32
    }
    __syncthreads();

    float4* outp = (float4*)(partials + ((size_t)c * nranges + r) * RANGE);
    for (int i = threadIdx.x; i < RANGE / 4; i += blockDim.x) outp[i] = b4[i];
}

// ---------------------------------------------------------------------------
// Reduce agg partials, add self-loop, fused GRU + output head:
//   s = dinv*(sum_c P[c][i] + w[i]),
//   out[i] = sum_j relu(sigmoid(-zp)*tanh(hp)) * Wout_j + bout.
// ---------------------------------------------------------------------------
__global__ void k_out(const float* __restrict__ partials, const float* __restrict__ dinv,
                      const float* __restrict__ w, const float* __restrict__ coeff,
                      const float* __restrict__ Wout, const float* __restrict__ bout,
                      float* __restrict__ out, int N, int nranges) {
    __shared__ float c[5 * HIDDEN];
    __shared__ float b0;
    if (threadIdx.x < 4 * HIDDEN) c[threadIdx.x] = coeff[threadIdx.x];
    if (threadIdx.x < HIDDEN) c[4 * HIDDEN + threadIdx.x] = Wout[threadIdx.x];
    if (threadIdx.x == 0) b0 = bout[0];
    __syncthreads();
    int i = blockIdx.x * blockDim.x + threadIdx.x;
    if (i < N) {
        int r = i >> RSHIFT, local = i & (RANGE - 1);
        const float* p = partials + (size_t)r * RANGE + local;
        float g = w[i];
        #pragma unroll
        for (int k = 0; k < G; ++k) g += p[(size_t)k * nranges * RANGE];
        float si = dinv[i] * g;
        float acc = b0;
        #pragma unroll
        for (int j = 0; j < HIDDEN; ++j) {
            float zp = fminf(fmaxf(si * c[j] + c[64 + j], -30.f), 30.f);
            float hp = fminf(fmaxf(si * c[128 + j] + c[192 + j], -15.f), 15.f);
            float a  = __expf(2.0f * hp);               // tanh(hp)=(a-1)/(a+1)
            float t  = (a - 1.0f) / (a + 1.0f);
            float zn = 1.0f / (1.0f + __expf(zp));      // 1 - sigmoid(zp)
            float hn = zn * t;
            hn = hn > 0.0f ? hn : 0.0f;
            acc = fmaf(hn, c[256 + j], acc);
        }
        out[i] = acc;
    }
}

extern "C" void kernel_launch(void* const* d_in, const int* in_sizes, int n_in,
                              void* d_out, int out_size, void* d_ws, size_t ws_size,
                              hipStream_t stream) {
    const float* x    = (const float*)d_in[0];
    const float* ew   = (const float*)d_in[1];
    const float* Wz   = (const float*)d_in[2];
    const float* bz   = (const float*)d_in[3];
    const float* Lz   = (const float*)d_in[4];
    const float* lbz  = (const float*)d_in[5];
    // d_in[6..9] = Wr, br, Lr, lbr — dead (H0 = 0 makes the R gate unused)
    const float* Wh   = (const float*)d_in[10];
    const float* bh   = (const float*)d_in[11];
    const float* Lh   = (const float*)d_in[12];
    const float* lbh  = (const float*)d_in[13];
    const float* Wout = (const float*)d_in[14];
    const float* bout = (const float*)d_in[15];
    const int*   eidx = (const int*)d_in[16];

    const int N = in_sizes[0];          // x is [N,1]  (100000 -> src fits 17 bits)
    const int E = in_sizes[1];          // edge_weight is [E]
    const int* src = eidx;              // edge_index[0]
    const int* dst = eidx + E;          // edge_index[1]

    const int nranges = (N + RANGE - 1) / RANGE;   // 7
    const int cap = (((E + G - 1) / G) + 15) & ~3; // comp slice capacity

    // Workspace (~105 MB of the 256 MiB d_ws):
    float* partials = (float*)d_ws;                                   // G*nranges*RANGE
    uint2* comp     = (uint2*)(partials + (size_t)G * nranges * RANGE); // nranges*G*cap
    float* dinv     = (float*)(comp + (size_t)nranges * G * cap);     // N
    float* w        = dinv + N;                                       // N
    float* coeff    = w + N;                                          // 4*HIDDEN
    int*   counts   = (int*)(coeff + 4 * HIDDEN);                     // nranges*G

    const int TB = 256;
    const int grid_bin = nranges * G;      // 224 blocks, 64 KB LDS each

    // Pass A: deg binning + edge compaction (7x edge read, XCD-L2-shared)
    k_binA<<<grid_bin, 1024, 0, stream>>>(dst, src, ew, partials, comp, counts,
                                          N, E, nranges, cap);
    // deg -> dinv, w = dinv*x; plus GRU coefficient fusion
    k_node<<<(N + TB - 1) / TB, TB, 0, stream>>>(x, partials, dinv, w, N, nranges,
                                                 Wz, bz, Lz, lbz, Wh, bh, Lh, lbh, coeff);
    // Pass B: aggregate over compacted edges (zero waste)
    k_binB<<<grid_bin, 1024, 0, stream>>>(comp, counts, w, partials, nranges, cap);
    // Reduce + fused GRU + output head
    k_out<<<(N + TB - 1) / TB, TB, 0, stream>>>(partials, dinv, w, coeff, Wout, bout,
                                                (float*)d_out, N, nranges);
}